// Round 5
// baseline (401.504 us; speedup 1.0000x reference)
//
#include <hip/hip_runtime.h>
#include <hip/hip_bf16.h>
#include <stdint.h>

#define ALPHA_ 0.2f
#define EPS_   1e-6f

typedef __attribute__((ext_vector_type(8))) short  short8;
typedef __attribute__((ext_vector_type(4))) float  float4v;

union U8 { short8 s8; unsigned int u[4]; uint4 v4; };

static __device__ __forceinline__ unsigned short f2bf(float x) {
    union { float f; unsigned int u; } c; c.f = x;
    return (unsigned short)((c.u + 0x7fffu + ((c.u >> 16) & 1u)) >> 16);
}

// ---------------- K0: WT in MFMA-B-fragment order ---------------------------
__global__ __launch_bounds__(256) void k_wt(const float* __restrict__ W,
                                            unsigned short* __restrict__ WTs) {
    const int g  = blockIdx.x * 256 + threadIdx.x;   // 8192 threads
    const int fb = g >> 9, kc = (g >> 6) & 7, l = g & 63;
    const int m = l & 15, quad = l >> 4;
    const int f = fb * 16 + m, d0 = kc * 32 + quad * 8;
    unsigned short v[8];
#pragma unroll
    for (int i = 0; i < 8; ++i) v[i] = f2bf(W[(d0 + i) * 256 + f]);
    uint4 o;
    o.x = (unsigned)v[0] | ((unsigned)v[1] << 16);
    o.y = (unsigned)v[2] | ((unsigned)v[3] << 16);
    o.z = (unsigned)v[4] | ((unsigned)v[5] << 16);
    o.w = (unsigned)v[6] | ((unsigned)v[7] << 16);
    *(uint4*)(WTs + (size_t)g * 8) = o;
}

// ---------------- K1: MFMA Wh = h@W; fused s1/s2; WhT [b][f][j] -------------
__global__ __launch_bounds__(256) void k_wh(const float* __restrict__ h,
                                            const unsigned short* __restrict__ WTs,
                                            const float* __restrict__ a,
                                            unsigned short* __restrict__ WhT,
                                            float* __restrict__ s1g,
                                            float* __restrict__ s2g) {
    __shared__ __align__(16) unsigned short A_lds[32][264];
    __shared__ __align__(16) unsigned short T_lds[256][44];
    __shared__ float s1p[32], s2p[32];
    const int t    = threadIdx.x;
    const int lane = t & 63;
    const int wv   = t >> 6;
    const int m    = lane & 15;
    const int quad = lane >> 4;
    const int r0   = blockIdx.x * 32;
    const int b    = r0 >> 11;
    const int j0   = r0 & 2047;

    if (t < 32) { s1p[t] = 0.f; s2p[t] = 0.f; }

#pragma unroll
    for (int k = 0; k < 8; ++k) {
        const int flat = t + k * 256;
        const int r  = flat >> 6;
        const int d4 = flat & 63;
        float4v hv = *(const float4v*)(h + (size_t)(r0 + r) * 256 + d4 * 4);
        uint2 pk;
        pk.x = (unsigned)f2bf(hv.x) | ((unsigned)f2bf(hv.y) << 16);
        pk.y = (unsigned)f2bf(hv.z) | ((unsigned)f2bf(hv.w) << 16);
        *(uint2*)&A_lds[r][d4 * 4] = pk;
    }
    __syncthreads();

    const int fbase = wv * 64;
    float4v acc[2][4];
#pragma unroll
    for (int it = 0; it < 2; ++it)
#pragma unroll
        for (int ft = 0; ft < 4; ++ft)
#pragma unroll
            for (int r = 0; r < 4; ++r) acc[it][ft][r] = 0.f;

    const unsigned short* wtb = WTs + (size_t)(wv * 4) * 4096 + lane * 8;

#pragma unroll
    for (int kc = 0; kc < 8; ++kc) {
        short8 af0 = *(const short8*)&A_lds[m][kc * 32 + quad * 8];
        short8 af1 = *(const short8*)&A_lds[16 + m][kc * 32 + quad * 8];
#pragma unroll
        for (int ft = 0; ft < 4; ++ft) {
            short8 bf = *(const short8*)(wtb + (size_t)ft * 4096 + kc * 512);
            acc[0][ft] = __builtin_amdgcn_mfma_f32_16x16x32_bf16(af0, bf, acc[0][ft], 0, 0, 0);
            acc[1][ft] = __builtin_amdgcn_mfma_f32_16x16x32_bf16(af1, bf, acc[1][ft], 0, 0, 0);
        }
    }

    float a1v[4], a2v[4];
#pragma unroll
    for (int ft = 0; ft < 4; ++ft) {
        a1v[ft] = a[fbase + ft * 16 + m];
        a2v[ft] = a[256 + fbase + ft * 16 + m];
    }
#pragma unroll
    for (int it = 0; it < 2; ++it) {
#pragma unroll
        for (int reg = 0; reg < 4; ++reg) {
            float v1 = 0.f, v2 = 0.f;
#pragma unroll
            for (int ft = 0; ft < 4; ++ft) {
                const float c = acc[it][ft][reg];
                v1 = fmaf(c, a1v[ft], v1);
                v2 = fmaf(c, a2v[ft], v2);
            }
            v1 += __shfl_xor(v1, 1); v2 += __shfl_xor(v2, 1);
            v1 += __shfl_xor(v1, 2); v2 += __shfl_xor(v2, 2);
            v1 += __shfl_xor(v1, 4); v2 += __shfl_xor(v2, 4);
            v1 += __shfl_xor(v1, 8); v2 += __shfl_xor(v2, 8);
            if (m == 0) {
                const int row = it * 16 + quad * 4 + reg;
                atomicAdd(&s1p[row], v1);
                atomicAdd(&s2p[row], v2);
            }
        }
    }

#pragma unroll
    for (int it = 0; it < 2; ++it)
#pragma unroll
        for (int ft = 0; ft < 4; ++ft)
#pragma unroll
            for (int reg = 0; reg < 4; ++reg)
                T_lds[fbase + ft * 16 + m][it * 16 + quad * 4 + reg] =
                    f2bf(acc[it][ft][reg]);

    {
        uint4 o0 = *(const uint4*)&T_lds[t][0];
        uint4 o1 = *(const uint4*)&T_lds[t][8];
        uint4 o2 = *(const uint4*)&T_lds[t][16];
        uint4 o3 = *(const uint4*)&T_lds[t][24];
        unsigned short* wto = WhT + ((size_t)(b * 256 + t) * 2048) + j0;
        *(uint4*)(wto + 0)  = o0;
        *(uint4*)(wto + 8)  = o1;
        *(uint4*)(wto + 16) = o2;
        *(uint4*)(wto + 24) = o3;
    }

    __syncthreads();
    if (t < 32) {
        s1g[(size_t)b * 2048 + j0 + t] = s1p[t];
        s2g[(size_t)b * 2048 + j0 + t] = s2p[t];
    }
}

// ---------------- K3: wave-private fused attention, zero sync ---------------
// 2048 blocks x 64 thr (1 wave). Wave = 16 i x 128 f, K-loop 64 chunks x 32 j.
// Lane(q,m) computes p[i0+m][j0+q*8..+8] == its own MFMA A-fragment. No LDS.
static __device__ __forceinline__ uint2 pquad(float4v av, float4v s2v,
                                              float s1, float& rs) {
    float e0 = s1 + s2v.x, e1 = s1 + s2v.y, e2 = s1 + s2v.z, e3 = s1 + s2v.w;
    e0 = fmaxf(e0, ALPHA_ * e0); e1 = fmaxf(e1, ALPHA_ * e1);
    e2 = fmaxf(e2, ALPHA_ * e2); e3 = fmaxf(e3, ALPHA_ * e3);
    const float p0 = (av.x + EPS_) * __expf(e0);
    const float p1 = (av.y + EPS_) * __expf(e1);
    const float p2 = (av.z + EPS_) * __expf(e2);
    const float p3 = (av.w + EPS_) * __expf(e3);
    rs += (p0 + p1) + (p2 + p3);
    uint2 r;
    r.x = (unsigned)f2bf(p0) | ((unsigned)f2bf(p1) << 16);
    r.y = (unsigned)f2bf(p2) | ((unsigned)f2bf(p3) << 16);
    return r;
}

__global__ __launch_bounds__(64) void k_attn(const float* __restrict__ adj,
                                             const unsigned short* __restrict__ WhT,
                                             const float* __restrict__ s1g,
                                             const float* __restrict__ s2g,
                                             float* __restrict__ out) {
    const int lane = threadIdx.x;
    const int m    = lane & 15;
    const int q    = lane >> 4;
    const int blk  = blockIdx.x;
    const int b    = blk & 7;            // XCD-pinned batch (L2 locality)
    const int fh   = (blk >> 3) & 1;     // f half
    const int it   = blk >> 4;           // 0..127
    const int i0   = it * 16;
    const int f0   = fh * 128;

    const float* adjp = adj + (size_t)(b * 2048 + i0 + m) * 2048 + q * 8;
    const float* s2p  = s2g + (size_t)b * 2048 + q * 8;
    const float  s1v  = s1g[(size_t)b * 2048 + i0 + m];
    const unsigned short* wtp =
        WhT + (size_t)(b * 256 + f0 + m) * 2048 + q * 8;

    float4v acc[8];
#pragma unroll
    for (int ft = 0; ft < 8; ++ft)
#pragma unroll
        for (int r = 0; r < 4; ++r) acc[ft][r] = 0.f;

    float rs = 0.f;

    // prologue: chunk-0 operands
    float4v a0 = *(const float4v*)(adjp);
    float4v a1 = *(const float4v*)(adjp + 4);
    float4v s0 = *(const float4v*)(s2p);
    float4v s1q = *(const float4v*)(s2p + 4);

#pragma unroll 2
    for (int ch = 0; ch < 64; ++ch) {
        const int j0 = ch * 32;
        const int jn = ((ch + 1) & 63) * 32;   // wrap: harmless reload

        // p == A-fragment, computed in place
        U8 af;
        uint2 qa = pquad(a0, s0, s1v, rs);
        uint2 qb = pquad(a1, s1q, s1v, rs);
        af.u[0] = qa.x; af.u[1] = qa.y; af.u[2] = qb.x; af.u[3] = qb.y;

        // register prefetch of next chunk (issued before the MFMA phase)
        a0  = *(const float4v*)(adjp + jn);
        a1  = *(const float4v*)(adjp + jn + 4);
        s0  = *(const float4v*)(s2p + jn);
        s1q = *(const float4v*)(s2p + jn + 4);

        // 8 B-fragments JIT from L2-resident WhT + 8 independent MFMAs
#pragma unroll
        for (int ft = 0; ft < 8; ++ft) {
            short8 bf = *(const short8*)(wtp + (size_t)ft * 16 * 2048 + j0);
            acc[ft] = __builtin_amdgcn_mfma_f32_16x16x32_bf16(af.s8, bf, acc[ft], 0, 0, 0);
        }
    }

    // full rowsum: quads hold disjoint j-slices of row i0+m
    rs += __shfl_xor(rs, 16);
    rs += __shfl_xor(rs, 32);

    // epilogue: C/D col = lane&15 (f), row = q*4+reg (i)
#pragma unroll
    for (int reg = 0; reg < 4; ++reg) {
        const int row = q * 4 + reg;
        const float inv = 1.0f / __shfl(rs, row);
#pragma unroll
        for (int ft = 0; ft < 8; ++ft) {
            out[(size_t)(b * 2048 + i0 + row) * 256 + f0 + ft * 16 + m] =
                acc[ft][reg] * inv;
        }
    }
}

extern "C" void kernel_launch(void* const* d_in, const int* in_sizes, int n_in,
                              void* d_out, int out_size, void* d_ws, size_t ws_size,
                              hipStream_t stream) {
    const float* h   = (const float*)d_in[0];   // (8,2048,256)
    const float* adj = (const float*)d_in[1];   // (8,2048,2048)
    const float* W   = (const float*)d_in[2];   // (256,256)
    const float* a   = (const float*)d_in[3];   // (512,1)
    float* out = (float*)d_out;                 // (8,2048,256)

    unsigned short* WhT = (unsigned short*)d_ws;                        // 8.4 MB
    unsigned short* WTs = (unsigned short*)((char*)d_ws + 8388608);     // 128 KB
    float*          s1  = (float*)((char*)d_ws + 8388608 + 131072);     // 64 KB
    float*          s2  = s1 + 16384;                                   // 64 KB

    k_wt  <<<dim3(32),   dim3(256), 0, stream>>>(W, WTs);
    k_wh  <<<dim3(512),  dim3(256), 0, stream>>>(h, WTs, a, WhT, s1, s2);
    k_attn<<<dim3(2048), dim3(64),  0, stream>>>(adj, WhT, s1, s2, out);
}

// Round 6
// 240.471 us; speedup vs baseline: 1.6697x; 1.6697x over previous
//
#include <hip/hip_runtime.h>
#include <hip/hip_bf16.h>
#include <stdint.h>

#define ALPHA_ 0.2f
#define EPS_   1e-6f

typedef __attribute__((ext_vector_type(8))) short  short8;
typedef __attribute__((ext_vector_type(4))) float  float4v;

static __device__ __forceinline__ unsigned short f2bf(float x) {
    union { float f; unsigned int u; } c; c.f = x;
    return (unsigned short)((c.u + 0x7fffu + ((c.u >> 16) & 1u)) >> 16);
}

// ---------------- K0: WT in MFMA-B-fragment order (for k_wh) ----------------
__global__ __launch_bounds__(256) void k_wt(const float* __restrict__ W,
                                            unsigned short* __restrict__ WTs) {
    const int g  = blockIdx.x * 256 + threadIdx.x;   // 8192 threads
    const int fb = g >> 9, kc = (g >> 6) & 7, l = g & 63;
    const int m = l & 15, quad = l >> 4;
    const int f = fb * 16 + m, d0 = kc * 32 + quad * 8;
    unsigned short v[8];
#pragma unroll
    for (int i = 0; i < 8; ++i) v[i] = f2bf(W[(d0 + i) * 256 + f]);
    uint4 o;
    o.x = (unsigned)v[0] | ((unsigned)v[1] << 16);
    o.y = (unsigned)v[2] | ((unsigned)v[3] << 16);
    o.z = (unsigned)v[4] | ((unsigned)v[5] << 16);
    o.w = (unsigned)v[6] | ((unsigned)v[7] << 16);
    *(uint4*)(WTs + (size_t)g * 8) = o;
}

// ---------------- K1: MFMA Wh = h@W; fused s1/s2; WhS in B-frag order -------
// WhS layout: [b][jc(64)][fb(16)][lane(64)][8 halves] -> k_attn B-load is a
// lane-contiguous 1KB read (no scatter).
__global__ __launch_bounds__(256) void k_wh(const float* __restrict__ h,
                                            const unsigned short* __restrict__ WTs,
                                            const float* __restrict__ a,
                                            unsigned short* __restrict__ WhS,
                                            float* __restrict__ s1g,
                                            float* __restrict__ s2g) {
    __shared__ __align__(16) unsigned short A_lds[32][264];   // pad 256->264
    __shared__ __align__(16) unsigned short T_lds[256][40];   // [f][j] pad 32->40
    __shared__ float s1p[32], s2p[32];
    const int t    = threadIdx.x;
    const int lane = t & 63;
    const int wv   = t >> 6;
    const int m    = lane & 15;
    const int quad = lane >> 4;
    const int r0   = blockIdx.x * 32;     // 512 blocks
    const int b    = blockIdx.x >> 6;
    const int jc   = blockIdx.x & 63;
    const int j0   = r0 & 2047;

    if (t < 32) { s1p[t] = 0.f; s2p[t] = 0.f; }

    // stage h tile fp32 -> bf16 LDS (coalesced float4)
#pragma unroll
    for (int k = 0; k < 8; ++k) {
        const int flat = t + k * 256;
        const int r  = flat >> 6;
        const int d4 = flat & 63;
        float4v hv = *(const float4v*)(h + (size_t)(r0 + r) * 256 + d4 * 4);
        uint2 pk;
        pk.x = (unsigned)f2bf(hv.x) | ((unsigned)f2bf(hv.y) << 16);
        pk.y = (unsigned)f2bf(hv.z) | ((unsigned)f2bf(hv.w) << 16);
        *(uint2*)&A_lds[r][d4 * 4] = pk;
    }
    __syncthreads();

    const int fbase = wv * 64;
    float4v acc[2][4];
#pragma unroll
    for (int it = 0; it < 2; ++it)
#pragma unroll
        for (int ft = 0; ft < 4; ++ft)
#pragma unroll
            for (int r = 0; r < 4; ++r) acc[it][ft][r] = 0.f;

    const unsigned short* wtb = WTs + (size_t)(wv * 4) * 4096 + lane * 8;

#pragma unroll
    for (int kc = 0; kc < 8; ++kc) {
        short8 af0 = *(const short8*)&A_lds[m][kc * 32 + quad * 8];
        short8 af1 = *(const short8*)&A_lds[16 + m][kc * 32 + quad * 8];
#pragma unroll
        for (int ft = 0; ft < 4; ++ft) {
            short8 bf = *(const short8*)(wtb + (size_t)ft * 4096 + kc * 512);
            acc[0][ft] = __builtin_amdgcn_mfma_f32_16x16x32_bf16(af0, bf, acc[0][ft], 0, 0, 0);
            acc[1][ft] = __builtin_amdgcn_mfma_f32_16x16x32_bf16(af1, bf, acc[1][ft], 0, 0, 0);
        }
    }

    // fused s1/s2
    float a1v[4], a2v[4];
#pragma unroll
    for (int ft = 0; ft < 4; ++ft) {
        a1v[ft] = a[fbase + ft * 16 + m];
        a2v[ft] = a[256 + fbase + ft * 16 + m];
    }
#pragma unroll
    for (int it = 0; it < 2; ++it) {
#pragma unroll
        for (int reg = 0; reg < 4; ++reg) {
            float v1 = 0.f, v2 = 0.f;
#pragma unroll
            for (int ft = 0; ft < 4; ++ft) {
                const float c = acc[it][ft][reg];
                v1 = fmaf(c, a1v[ft], v1);
                v2 = fmaf(c, a2v[ft], v2);
            }
            v1 += __shfl_xor(v1, 1); v2 += __shfl_xor(v2, 1);
            v1 += __shfl_xor(v1, 2); v2 += __shfl_xor(v2, 2);
            v1 += __shfl_xor(v1, 4); v2 += __shfl_xor(v2, 4);
            v1 += __shfl_xor(v1, 8); v2 += __shfl_xor(v2, 8);
            if (m == 0) {
                const int row = it * 16 + quad * 4 + reg;
                atomicAdd(&s1p[row], v1);
                atomicAdd(&s2p[row], v2);
            }
        }
    }

    // C -> T_lds[f][j]
#pragma unroll
    for (int it = 0; it < 2; ++it)
#pragma unroll
        for (int ft = 0; ft < 4; ++ft)
#pragma unroll
            for (int reg = 0; reg < 4; ++reg)
                T_lds[fbase + ft * 16 + m][it * 16 + quad * 4 + reg] =
                    f2bf(acc[it][ft][reg]);

    __syncthreads();   // cross-wave T_lds reads below

    // swizzled store: WhS[(b*64+jc)*16 + fb][l] = T_lds[fb*16 + (l&15)][(l>>4)*8 ..+8]
#pragma unroll
    for (int e = 0; e < 4; ++e) {
        const int idx = e * 256 + t;
        const int fb = idx >> 6, l = idx & 63;
        uint4 v = *(const uint4*)&T_lds[fb * 16 + (l & 15)][(l >> 4) * 8];
        *(uint4*)(WhS + ((size_t)(b * 64 + jc) * 16 + fb) * 512 + l * 8) = v;
    }

    if (t < 32) {
        s1g[(size_t)b * 2048 + j0 + t] = s1p[t];
        s2g[(size_t)b * 2048 + j0 + t] = s2p[t];
    }
}

// ---------------- K3: fused softmax aggregation, high-TLP m97 structure -----
// 1024 blocks x 256 thr (4 blocks/CU). Block = 32 i x 128 f (f-split x2).
// 16 steps of 128 j: p -> pbuf[cur] (dbuf), 1 barrier, MFMA w/ coalesced B.
static __device__ __forceinline__ uint2 pquad(float4v av, float4v s2v,
                                              float s1, float& rs) {
    float e0 = s1 + s2v.x, e1 = s1 + s2v.y, e2 = s1 + s2v.z, e3 = s1 + s2v.w;
    e0 = fmaxf(e0, ALPHA_ * e0); e1 = fmaxf(e1, ALPHA_ * e1);
    e2 = fmaxf(e2, ALPHA_ * e2); e3 = fmaxf(e3, ALPHA_ * e3);
    const float p0 = (av.x + EPS_) * __expf(e0);
    const float p1 = (av.y + EPS_) * __expf(e1);
    const float p2 = (av.z + EPS_) * __expf(e2);
    const float p3 = (av.w + EPS_) * __expf(e3);
    rs += (p0 + p1) + (p2 + p3);
    uint2 r;
    r.x = (unsigned)f2bf(p0) | ((unsigned)f2bf(p1) << 16);
    r.y = (unsigned)f2bf(p2) | ((unsigned)f2bf(p3) << 16);
    return r;
}

__global__ __launch_bounds__(256, 4) void k_attn(const float* __restrict__ adj,
                                                 const unsigned short* __restrict__ WhS,
                                                 const float* __restrict__ s1g,
                                                 const float* __restrict__ s2g,
                                                 float* __restrict__ out) {
    __shared__ __align__(16) unsigned short pbuf[2][32][140];  // pad 128->140
    __shared__ float rsum_lds[32];

    const int t    = threadIdx.x;
    const int lane = t & 63;
    const int wv   = t >> 6;
    const int m    = lane & 15;
    const int quad = lane >> 4;
    const int blk  = blockIdx.x;
    const int b    = blk & 7;            // XCD-pinned batch
    const int fh   = (blk >> 3) & 1;     // f half (same-XCD neighbor shares adj)
    const int i0   = (blk >> 4) * 32;    // 64 i-tiles

    const int ip = t >> 3;               // 0..31
    const int jq = t & 7;                // 0..7

    const float* adjp = adj + (size_t)(b * 2048 + i0 + ip) * 2048 + jq * 4;
    const float* s2p  = s2g + (size_t)b * 2048 + jq * 4;
    const float  s1v  = s1g[(size_t)b * 2048 + i0 + ip];

    const int fbb = fh * 8 + wv * 2;     // this wave's first f-block (of 16)
    const unsigned short* whs = WhS + (size_t)b * 64 * 16 * 512;

    float4v acc[2][2];   // [it][ft]
#pragma unroll
    for (int it = 0; it < 2; ++it)
#pragma unroll
        for (int ft = 0; ft < 2; ++ft)
#pragma unroll
            for (int r = 0; r < 4; ++r) acc[it][ft][r] = 0.f;

    float rs = 0.f;

    // prologue: step-0 adj/s2 in registers (coalesced 128B-per-row segments)
    float4v adjv[4], s2v[4];
#pragma unroll
    for (int c = 0; c < 4; ++c) {
        adjv[c] = *(const float4v*)(adjp + c * 32);
        s2v[c]  = *(const float4v*)(s2p + c * 32);
    }

    for (int step = 0; step < 16; ++step) {
        const int cur = step & 1;

        // ---- p (fp32) -> bf16, ds_write into pbuf[cur] ----
#pragma unroll
        for (int c = 0; c < 4; ++c) {
            uint2 pk = pquad(adjv[c], s2v[c], s1v, rs);
            *(uint2*)&pbuf[cur][ip][jq * 4 + c * 32] = pk;
        }

        // register-prefetch next step
        const int ns = (step + 1) & 15;  // wrap: harmless reload
#pragma unroll
        for (int c = 0; c < 4; ++c) {
            adjv[c] = *(const float4v*)(adjp + (size_t)ns * 128 + c * 32);
            s2v[c]  = *(const float4v*)(s2p + (size_t)ns * 128 + c * 32);
        }

        __syncthreads();   // pbuf[cur] visible; dbuf -> one barrier per step

        // ---- MFMA: B-frags are lane-contiguous 1KB L2 reads ----
#pragma unroll
        for (int kc = 0; kc < 4; ++kc) {
            const unsigned short* bp =
                whs + ((size_t)((step * 4 + kc) * 16 + fbb)) * 512 + lane * 8;
            short8 bf0 = *(const short8*)bp;
            short8 bf1 = *(const short8*)(bp + 512);
            short8 af0 = *(const short8*)&pbuf[cur][m][kc * 32 + quad * 8];
            short8 af1 = *(const short8*)&pbuf[cur][16 + m][kc * 32 + quad * 8];
            acc[0][0] = __builtin_amdgcn_mfma_f32_16x16x32_bf16(af0, bf0, acc[0][0], 0, 0, 0);
            acc[0][1] = __builtin_amdgcn_mfma_f32_16x16x32_bf16(af0, bf1, acc[0][1], 0, 0, 0);
            acc[1][0] = __builtin_amdgcn_mfma_f32_16x16x32_bf16(af1, bf0, acc[1][0], 0, 0, 0);
            acc[1][1] = __builtin_amdgcn_mfma_f32_16x16x32_bf16(af1, bf1, acc[1][1], 0, 0, 0);
        }
    }

    // rowsum: lanes xor 1,2,4 share ip (t = ip*8 + jq)
    rs += __shfl_xor(rs, 1);
    rs += __shfl_xor(rs, 2);
    rs += __shfl_xor(rs, 4);
    if (jq == 0) rsum_lds[ip] = rs;
    __syncthreads();

    // epilogue: C/D col = lane&15 (f), row = quad*4+reg (i), +16 per it
#pragma unroll
    for (int reg = 0; reg < 4; ++reg) {
        const int row  = quad * 4 + reg;
        const float i0v = 1.0f / rsum_lds[row];
        const float i1v = 1.0f / rsum_lds[16 + row];
#pragma unroll
        for (int ft = 0; ft < 2; ++ft) {
            const int f = fh * 128 + wv * 32 + ft * 16 + m;
            out[(size_t)(b * 2048 + i0 + row) * 256 + f]      = acc[0][ft][reg] * i0v;
            out[(size_t)(b * 2048 + i0 + 16 + row) * 256 + f] = acc[1][ft][reg] * i1v;
        }
    }
}

extern "C" void kernel_launch(void* const* d_in, const int* in_sizes, int n_in,
                              void* d_out, int out_size, void* d_ws, size_t ws_size,
                              hipStream_t stream) {
    const float* h   = (const float*)d_in[0];   // (8,2048,256)
    const float* adj = (const float*)d_in[1];   // (8,2048,2048)
    const float* W   = (const float*)d_in[2];   // (256,256)
    const float* a   = (const float*)d_in[3];   // (512,1)
    float* out = (float*)d_out;                 // (8,2048,256)

    unsigned short* WhS = (unsigned short*)d_ws;                        // 8.4 MB
    unsigned short* WTs = (unsigned short*)((char*)d_ws + 8388608);     // 128 KB
    float*          s1  = (float*)((char*)d_ws + 8388608 + 131072);     // 64 KB
    float*          s2  = s1 + 16384;                                   // 64 KB

    k_wt  <<<dim3(32),   dim3(256), 0, stream>>>(W, WTs);
    k_wh  <<<dim3(512),  dim3(256), 0, stream>>>(h, WTs, a, WhS, s1, s2);
    k_attn<<<dim3(1024), dim3(256), 0, stream>>>(adj, WhS, s1, s2, out);
}